// Round 9
// baseline (268.688 us; speedup 1.0000x reference)
//
#include <hip/hip_runtime.h>
#include <hip/hip_bf16.h>
#include <stdint.h>

typedef __bf16 bf16x8_t __attribute__((ext_vector_type(8)));
typedef float f32x4_t __attribute__((ext_vector_type(4)));

__device__ __forceinline__ float b2f(unsigned short u) {
    union { uint32_t i; float f; } x; x.i = ((uint32_t)u) << 16; return x.f;
}
__device__ __forceinline__ unsigned short f2b(float f) {
    union { float f; uint32_t i; } x; x.f = f;
    uint32_t r = (x.i + 0x7fffu + ((x.i >> 16) & 1u)) >> 16;
    return (unsigned short)r;
}
__device__ __forceinline__ void up2(uint32_t d, float& lo, float& hi) {
    union { uint32_t u; float f; } a, b;
    a.u = d << 16; b.u = d & 0xffff0000u;
    lo = a.f; hi = b.f;
}

#define QSCALE 0.17677669529663687f  /* 1/sqrt(32) */
#define NQ 50000

// Merged prep: feats->bf16, qkv_w (q rows pre-scaled)->bf16, proj_w->bf16, scaled qkv_b copy.
__global__ void prep_all(const float* __restrict__ feats, const float* __restrict__ qkv_w,
                         const float* __restrict__ proj_w, const float* __restrict__ qkv_b,
                         unsigned short* __restrict__ featsb, unsigned short* __restrict__ qkvwb,
                         unsigned short* __restrict__ projwb, float* __restrict__ qkvbS) {
    const int idx = blockIdx.x * 256 + threadIdx.x;
    const int NF = NQ * 256 / 4;
    if (idx < NF) {
        const int e = idx * 4;
        const float4 v = *reinterpret_cast<const float4*>(feats + e);
        ushort4 o;
        o.x = f2b(v.x); o.y = f2b(v.y); o.z = f2b(v.z); o.w = f2b(v.w);
        *reinterpret_cast<ushort4*>(featsb + e) = o;
    } else if (idx < NF + 49152) {
        const int e = (idx - NF) * 4;
        const float4 v = *reinterpret_cast<const float4*>(qkv_w + e);
        const float sc = (e >> 8) < 256 ? QSCALE : 1.f;
        ushort4 o;
        o.x = f2b(v.x * sc); o.y = f2b(v.y * sc); o.z = f2b(v.z * sc); o.w = f2b(v.w * sc);
        *reinterpret_cast<ushort4*>(qkvwb + e) = o;
    } else if (idx < NF + 49152 + 16384) {
        const int e = (idx - NF - 49152) * 4;
        const float4 v = *reinterpret_cast<const float4*>(proj_w + e);
        ushort4 o;
        o.x = f2b(v.x); o.y = f2b(v.y); o.z = f2b(v.z); o.w = f2b(v.w);
        *reinterpret_cast<ushort4*>(projwb + e) = o;
    } else if (idx < NF + 49152 + 16384 + 192) {
        const int e = (idx - NF - 49152 - 16384) * 4;
        float4 v = *reinterpret_cast<const float4*>(qkv_b + e);
        if (e < 256) { v.x *= QSCALE; v.y *= QSCALE; v.z *= QSCALE; v.w *= QSCALE; }
        *reinterpret_cast<float4*>(qkvbS + e) = v;
    }
}

// C[m,n] = sum_k A[m,k]*W[n,k] + bias[n]; 128x128 tile, BK=64, XOR-swizzled LDS,
// XCD-swizzled 1D grid.
// OUT_MODE 0: fp32 row-major C (MxNn).
// OUT_MODE 1: bf16 head-major qkv: addr = sec*M*256 + h*M*32 + row*32 + d.
// A_HM: A is bf16 head-major [h][row][32].
template <int OUT_MODE, bool A_HM>
__launch_bounds__(256, 2)
__global__ void gemm_bf16(const unsigned short* __restrict__ A,
                          const unsigned short* __restrict__ W,
                          const float* __restrict__ bias,
                          void* __restrict__ Cout,
                          int M, int Nn, int Kk) {
    const int nCol = Nn >> 7;
    const int p = blockIdx.x;
    const int xcd = p & 7;
    const int q = p >> 3;
    const int c = q % nCol;
    const int rr = q / nCol;
    const int r = rr * 8 + xcd;
    const int blockRow = r * 128;
    if (blockRow >= M) return;
    const int blockCol = c * 128;

    __shared__ unsigned short As[128 * 64];
    __shared__ unsigned short Bs[128 * 64];
    const int t = threadIdx.x;
    const int w = t >> 6;
    const int l = t & 63;
    const int wm = w >> 1, wn = w & 1;

    f32x4_t acc[4][4];
#pragma unroll
    for (int i = 0; i < 4; ++i)
#pragma unroll
        for (int j = 0; j < 4; ++j) acc[i][j] = (f32x4_t)0.f;

    const int srow = t >> 3;
    const int scol = (((t & 7) ^ ((t >> 3) & 7)) * 8);

    for (int k0 = 0; k0 < Kk; k0 += 64) {
#pragma unroll
        for (int cc = 0; cc < 4; ++cc) {
            int arow = blockRow + cc * 32 + srow;
            arow = arow < M ? arow : M - 1;
            const int ak = k0 + scol;
            const unsigned short* ga = A_HM
                ? A + (size_t)(ak >> 5) * M * 32 + (size_t)arow * 32 + (ak & 31)
                : A + (size_t)arow * Kk + ak;
            const int brow = blockCol + cc * 32 + srow;
            const unsigned short* gb = W + (size_t)brow * Kk + k0 + scol;
            unsigned short* la = &As[cc * 2048 + w * 512];
            unsigned short* lb = &Bs[cc * 2048 + w * 512];
            __builtin_amdgcn_global_load_lds((const __attribute__((address_space(1))) void*)ga,
                                             (__attribute__((address_space(3))) void*)la, 16, 0, 0);
            __builtin_amdgcn_global_load_lds((const __attribute__((address_space(1))) void*)gb,
                                             (__attribute__((address_space(3))) void*)lb, 16, 0, 0);
        }
        __syncthreads();
        const int l15 = l & 15;
        const int lk = l >> 4;
        const int key = l & 7;
#pragma unroll
        for (int kc = 0; kc < 2; ++kc) {
            bf16x8_t af[4], bfr[4];
            const int cb = kc * 4 + lk;
            const int kof = (cb ^ key) * 8;
#pragma unroll
            for (int i = 0; i < 4; ++i) {
                af[i]  = *reinterpret_cast<const bf16x8_t*>(&As[(wm * 64 + i * 16 + l15) * 64 + kof]);
                bfr[i] = *reinterpret_cast<const bf16x8_t*>(&Bs[(wn * 64 + i * 16 + l15) * 64 + kof]);
            }
#pragma unroll
            for (int i = 0; i < 4; ++i)
#pragma unroll
                for (int j = 0; j < 4; ++j)
                    acc[i][j] = __builtin_amdgcn_mfma_f32_16x16x32_bf16(af[i], bfr[j], acc[i][j], 0, 0, 0);
        }
        __syncthreads();
    }

    const int lr = (l >> 4) * 4;
    const int lc = l & 15;
#pragma unroll
    for (int i = 0; i < 4; ++i) {
#pragma unroll
        for (int j = 0; j < 4; ++j) {
            const int col = blockCol + wn * 64 + j * 16 + lc;
            const float bz = bias[col];
#pragma unroll
            for (int rg = 0; rg < 4; ++rg) {
                const int row = blockRow + wm * 64 + i * 16 + lr + rg;
                if (row < M) {
                    const float val = acc[i][j][rg] + bz;
                    if (OUT_MODE == 0) {
                        ((float*)Cout)[(size_t)row * Nn + col] = val;
                    } else {
                        const int sec = col >> 8;
                        const int hh = (col >> 5) & 7;
                        const int d = col & 31;
                        ((unsigned short*)Cout)[(size_t)sec * M * 256 + (size_t)hh * M * 32
                                                + (size_t)row * 32 + d] = f2b(val);
                    }
                }
            }
        }
    }
}

// Pass 1 via MFMA: block -> head h = blockIdx&7 (XCD-pinned). 4 waves x 16 queries.
// ALL 16 gathered A-fragments preloaded into registers (16 outstanding loads/wave)
// before the MFMA chain — the kernel is gather-latency-bound otherwise (R8: VGPR=32,
// ~2 loads in flight, 50 us at 14% HBM / 21% VALU / 5% MFMA).
__launch_bounds__(256, 4)
__global__ void attn_logits4(const unsigned short* __restrict__ qh,
                             const unsigned short* __restrict__ kh,
                             const int* __restrict__ index_1,
                             unsigned short* __restrict__ wh) {
    const int h = blockIdx.x & 7;
    const int slice = blockIdx.x >> 3;
    const int w = threadIdx.x >> 6;
    const int l = threadIdx.x & 63;
    const int col = l & 15;
    const int krow = l >> 4;
    const int qbase = slice * 64 + w * 16;

    const unsigned short* qhb = qh + (size_t)h * NQ * 32;
    const unsigned short* khb = kh + (size_t)h * NQ * 32;

    int qcol = qbase + col; qcol = qcol < NQ ? qcol : NQ - 1;
    const bf16x8_t bfrag = *reinterpret_cast<const bf16x8_t*>(qhb + (size_t)qcol * 32 + krow * 8);

    int idx[16];
#pragma unroll
    for (int j = 0; j < 16; ++j) {
        int qj = qbase + j; qj = qj < NQ ? qj : NQ - 1;
        idx[j] = index_1[(size_t)qj * 16 + col];
    }

    // phase 1: issue all 16 gathers (independent, 16 outstanding)
    bf16x8_t afr[16];
#pragma unroll
    for (int j = 0; j < 16; ++j)
        afr[j] = *reinterpret_cast<const bf16x8_t*>(khb + (size_t)idx[j] * 32 + krow * 8);

    // phase 2: MFMA chain, keep own column
    float s0 = 0.f, s1 = 0.f, s2 = 0.f, s3 = 0.f;
#pragma unroll
    for (int j = 0; j < 16; ++j) {
        const f32x4_t d = __builtin_amdgcn_mfma_f32_16x16x32_bf16(afr[j], bfrag, (f32x4_t)0.f, 0, 0, 0);
        const bool mine = (col == j);
        s0 = mine ? d[0] : s0;
        s1 = mine ? d[1] : s1;
        s2 = mine ? d[2] : s2;
        s3 = mine ? d[3] : s3;
    }

    float mx = fmaxf(fmaxf(s0, s1), fmaxf(s2, s3));
    mx = fmaxf(mx, __shfl_xor(mx, 16, 64));
    mx = fmaxf(mx, __shfl_xor(mx, 32, 64));
    float e0 = __expf(s0 - mx), e1 = __expf(s1 - mx), e2 = __expf(s2 - mx), e3 = __expf(s3 - mx);
    float sm = e0 + e1 + e2 + e3;
    sm += __shfl_xor(sm, 16, 64);
    sm += __shfl_xor(sm, 32, 64);
    const float inv = 1.f / sm;

    if (qbase + col < NQ) {
        const uint32_t d0 = (uint32_t)f2b(e0 * inv) | ((uint32_t)f2b(e1 * inv) << 16);
        const uint32_t d1 = (uint32_t)f2b(e2 * inv) | ((uint32_t)f2b(e3 * inv) << 16);
        *reinterpret_cast<uint2*>(wh + (size_t)h * NQ * 16 + (size_t)(qbase + col) * 16 + krow * 4)
            = make_uint2(d0, d1);
    }
}

// Pass 2 (head-split): x[i] (head h part) = sum_m w[h][i][m] * vh[h][nbr[m]].
__launch_bounds__(256, 4)
__global__ void attn_out3(const unsigned short* __restrict__ vh,
                          const unsigned short* __restrict__ wh,
                          const int* __restrict__ index_1,
                          unsigned short* __restrict__ xh) {
    const int h = blockIdx.x & 7;
    const int slice = blockIdx.x >> 3;
    const int w = threadIdx.x >> 6;
    const int l = threadIdx.x & 63;
    const int g = l >> 3;
    const int p = l & 7;
    int i = slice * 32 + w * 8 + g;
    const bool valid = i < NQ;
    if (!valid) i = 0;

    const int4* ip = reinterpret_cast<const int4*>(index_1 + (size_t)i * 16);
    const int4 n0 = ip[0], n1 = ip[1], n2 = ip[2], n3 = ip[3];
    const int nbr[16] = { n0.x, n0.y, n0.z, n0.w, n1.x, n1.y, n1.z, n1.w,
                          n2.x, n2.y, n2.z, n2.w, n3.x, n3.y, n3.z, n3.w };

    const uint32_t* whp = (const uint32_t*)wh + (size_t)h * NQ * 8 + (size_t)i * 8;
    const uint4 w0 = *reinterpret_cast<const uint4*>(whp);
    const uint4 w1 = *reinterpret_cast<const uint4*>(whp + 4);
    const uint32_t wd[8] = { w0.x, w0.y, w0.z, w0.w, w1.x, w1.y, w1.z, w1.w };
    float wt[16];
#pragma unroll
    for (int j = 0; j < 8; ++j) up2(wd[j], wt[2 * j], wt[2 * j + 1]);

    const unsigned short* vhb = vh + (size_t)h * NQ * 32;
    float ax = 0.f, ay = 0.f, az = 0.f, aw = 0.f;
#pragma unroll
    for (int m = 0; m < 16; ++m) {
        const ushort4 vu = *reinterpret_cast<const ushort4*>(vhb + (size_t)nbr[m] * 32 + p * 4);
        ax += wt[m] * b2f(vu.x); ay += wt[m] * b2f(vu.y);
        az += wt[m] * b2f(vu.z); aw += wt[m] * b2f(vu.w);
    }
    if (valid) {
        ushort4 o;
        o.x = f2b(ax); o.y = f2b(ay); o.z = f2b(az); o.w = f2b(aw);
        *reinterpret_cast<ushort4*>(xh + (size_t)h * NQ * 32 + (size_t)i * 32 + p * 4) = o;
    }
}

extern "C" void kernel_launch(void* const* d_in, const int* in_sizes, int n_in,
                              void* d_out, int out_size, void* d_ws, size_t ws_size,
                              hipStream_t stream) {
    const float* feats   = (const float*)d_in[0];
    const int*   index_1 = (const int*)d_in[3];
    const float* qkv_w   = (const float*)d_in[6];
    const float* qkv_b   = (const float*)d_in[7];
    const float* proj_w  = (const float*)d_in[8];
    const float* proj_b  = (const float*)d_in[9];
    float* out = (float*)d_out;

    const int N = NQ, DIM = 256, QKVD = 768;

    unsigned short* featsb = (unsigned short*)d_ws;                // N*256
    unsigned short* qkvwb  = featsb + (size_t)N * DIM;             // 768*256
    unsigned short* projwb = qkvwb + (size_t)QKVD * DIM;           // 256*256
    float*          qkvbS  = (float*)(projwb + (size_t)DIM * DIM); // 768 floats
    unsigned short* qkvh   = (unsigned short*)(qkvbS + QKVD);      // 3*N*256 head-major q|k|v
    unsigned short* qh     = qkvh;
    unsigned short* kh     = qkvh + (size_t)N * DIM;
    unsigned short* vh     = qkvh + (size_t)2 * N * DIM;
    unsigned short* xh     = qkvh + (size_t)3 * N * DIM;           // N*256 head-major
    unsigned short* wh     = xh + (size_t)N * DIM;                 // N*128 head-major

    const int prepQuads = N * 256 / 4 + 49152 + 16384 + 192;
    prep_all<<<(prepQuads + 255) / 256, 256, 0, stream>>>(
        feats, qkv_w, proj_w, qkv_b, featsb, qkvwb, projwb, qkvbS);

    const int nRow = (N + 127) / 128;           // 391
    const int nRowPad = ((nRow + 7) / 8) * 8;   // 392
    const int logitsBlocks = ((N + 63) / 64) * 8;  // 782 * 8
    const int outBlocks    = ((N + 31) / 32) * 8;  // 1563 * 8

    // 1) qkv = feats @ qkv_w.T + qkv_bS -> head-major q|k|v bf16 (q pre-scaled)
    gemm_bf16<1, false><<<nRowPad * (QKVD / 128), 256, 0, stream>>>(featsb, qkvwb, qkvbS, qkvh, N, QKVD, DIM);
    // 2a) logits + softmax -> weights (head-split, XCD-pinned, MFMA, preloaded gathers)
    attn_logits4<<<logitsBlocks, 256, 0, stream>>>(qh, kh, index_1, wh);
    // 2b) weighted V gather -> x (head-split, XCD-pinned)
    attn_out3<<<outBlocks, 256, 0, stream>>>(vh, wh, index_1, xh);
    // 3) out = x @ proj_w.T + proj_b (fp32), A head-major
    gemm_bf16<0, true><<<nRowPad * (DIM / 128), 256, 0, stream>>>(xh, projwb, proj_b, out, N, DIM, DIM);
}

// Round 11
// 260.682 us; speedup vs baseline: 1.0307x; 1.0307x over previous
//
#include <hip/hip_runtime.h>
#include <hip/hip_bf16.h>
#include <stdint.h>

typedef __bf16 bf16x8_t __attribute__((ext_vector_type(8)));
typedef float f32x4_t __attribute__((ext_vector_type(4)));

__device__ __forceinline__ float b2f(unsigned short u) {
    union { uint32_t i; float f; } x; x.i = ((uint32_t)u) << 16; return x.f;
}
__device__ __forceinline__ unsigned short f2b(float f) {
    union { float f; uint32_t i; } x; x.f = f;
    uint32_t r = (x.i + 0x7fffu + ((x.i >> 16) & 1u)) >> 16;
    return (unsigned short)r;
}
__device__ __forceinline__ void up2(uint32_t d, float& lo, float& hi) {
    union { uint32_t u; float f; } a, b;
    a.u = d << 16; b.u = d & 0xffff0000u;
    lo = a.f; hi = b.f;
}

#define QSCALE 0.17677669529663687f  /* 1/sqrt(32) */
#define NQ 50000

// Merged prep: feats->bf16, qkv_w (q rows pre-scaled)->bf16, proj_w->bf16, scaled qkv_b copy.
__global__ void prep_all(const float* __restrict__ feats, const float* __restrict__ qkv_w,
                         const float* __restrict__ proj_w, const float* __restrict__ qkv_b,
                         unsigned short* __restrict__ featsb, unsigned short* __restrict__ qkvwb,
                         unsigned short* __restrict__ projwb, float* __restrict__ qkvbS) {
    const int idx = blockIdx.x * 256 + threadIdx.x;
    const int NF = NQ * 256 / 4;
    if (idx < NF) {
        const int e = idx * 4;
        const float4 v = *reinterpret_cast<const float4*>(feats + e);
        ushort4 o;
        o.x = f2b(v.x); o.y = f2b(v.y); o.z = f2b(v.z); o.w = f2b(v.w);
        *reinterpret_cast<ushort4*>(featsb + e) = o;
    } else if (idx < NF + 49152) {
        const int e = (idx - NF) * 4;
        const float4 v = *reinterpret_cast<const float4*>(qkv_w + e);
        const float sc = (e >> 8) < 256 ? QSCALE : 1.f;
        ushort4 o;
        o.x = f2b(v.x * sc); o.y = f2b(v.y * sc); o.z = f2b(v.z * sc); o.w = f2b(v.w * sc);
        *reinterpret_cast<ushort4*>(qkvwb + e) = o;
    } else if (idx < NF + 49152 + 16384) {
        const int e = (idx - NF - 49152) * 4;
        const float4 v = *reinterpret_cast<const float4*>(proj_w + e);
        ushort4 o;
        o.x = f2b(v.x); o.y = f2b(v.y); o.z = f2b(v.z); o.w = f2b(v.w);
        *reinterpret_cast<ushort4*>(projwb + e) = o;
    } else if (idx < NF + 49152 + 16384 + 192) {
        const int e = (idx - NF - 49152 - 16384) * 4;
        float4 v = *reinterpret_cast<const float4*>(qkv_b + e);
        if (e < 256) { v.x *= QSCALE; v.y *= QSCALE; v.z *= QSCALE; v.w *= QSCALE; }
        *reinterpret_cast<float4*>(qkvbS + e) = v;
    }
}

// C[m,n] = sum_k A[m,k]*W[n,k] + bias[n]; 128x128 tile, BK=64, XOR-swizzled LDS,
// XCD-swizzled 1D grid.
// OUT_MODE 0: fp32 row-major C (MxNn).
// OUT_MODE 1: bf16 head-major qkv: addr = sec*M*256 + h*M*32 + row*32 + d.
// A_HM: A is bf16 head-major [h][row][32].
template <int OUT_MODE, bool A_HM>
__launch_bounds__(256, 2)
__global__ void gemm_bf16(const unsigned short* __restrict__ A,
                          const unsigned short* __restrict__ W,
                          const float* __restrict__ bias,
                          void* __restrict__ Cout,
                          int M, int Nn, int Kk) {
    const int nCol = Nn >> 7;
    const int p = blockIdx.x;
    const int xcd = p & 7;
    const int q = p >> 3;
    const int c = q % nCol;
    const int rr = q / nCol;
    const int r = rr * 8 + xcd;
    const int blockRow = r * 128;
    if (blockRow >= M) return;
    const int blockCol = c * 128;

    __shared__ unsigned short As[128 * 64];
    __shared__ unsigned short Bs[128 * 64];
    const int t = threadIdx.x;
    const int w = t >> 6;
    const int l = t & 63;
    const int wm = w >> 1, wn = w & 1;

    f32x4_t acc[4][4];
#pragma unroll
    for (int i = 0; i < 4; ++i)
#pragma unroll
        for (int j = 0; j < 4; ++j) acc[i][j] = (f32x4_t)0.f;

    const int srow = t >> 3;
    const int scol = (((t & 7) ^ ((t >> 3) & 7)) * 8);

    for (int k0 = 0; k0 < Kk; k0 += 64) {
#pragma unroll
        for (int cc = 0; cc < 4; ++cc) {
            int arow = blockRow + cc * 32 + srow;
            arow = arow < M ? arow : M - 1;
            const int ak = k0 + scol;
            const unsigned short* ga = A_HM
                ? A + (size_t)(ak >> 5) * M * 32 + (size_t)arow * 32 + (ak & 31)
                : A + (size_t)arow * Kk + ak;
            const int brow = blockCol + cc * 32 + srow;
            const unsigned short* gb = W + (size_t)brow * Kk + k0 + scol;
            unsigned short* la = &As[cc * 2048 + w * 512];
            unsigned short* lb = &Bs[cc * 2048 + w * 512];
            __builtin_amdgcn_global_load_lds((const __attribute__((address_space(1))) void*)ga,
                                             (__attribute__((address_space(3))) void*)la, 16, 0, 0);
            __builtin_amdgcn_global_load_lds((const __attribute__((address_space(1))) void*)gb,
                                             (__attribute__((address_space(3))) void*)lb, 16, 0, 0);
        }
        __syncthreads();
        const int l15 = l & 15;
        const int lk = l >> 4;
        const int key = l & 7;
#pragma unroll
        for (int kc = 0; kc < 2; ++kc) {
            bf16x8_t af[4], bfr[4];
            const int cb = kc * 4 + lk;
            const int kof = (cb ^ key) * 8;
#pragma unroll
            for (int i = 0; i < 4; ++i) {
                af[i]  = *reinterpret_cast<const bf16x8_t*>(&As[(wm * 64 + i * 16 + l15) * 64 + kof]);
                bfr[i] = *reinterpret_cast<const bf16x8_t*>(&Bs[(wn * 64 + i * 16 + l15) * 64 + kof]);
            }
#pragma unroll
            for (int i = 0; i < 4; ++i)
#pragma unroll
                for (int j = 0; j < 4; ++j)
                    acc[i][j] = __builtin_amdgcn_mfma_f32_16x16x32_bf16(af[i], bfr[j], acc[i][j], 0, 0, 0);
        }
        __syncthreads();
    }

    const int lr = (l >> 4) * 4;
    const int lc = l & 15;
#pragma unroll
    for (int i = 0; i < 4; ++i) {
#pragma unroll
        for (int j = 0; j < 4; ++j) {
            const int col = blockCol + wn * 64 + j * 16 + lc;
            const float bz = bias[col];
#pragma unroll
            for (int rg = 0; rg < 4; ++rg) {
                const int row = blockRow + wm * 64 + i * 16 + lr + rg;
                if (row < M) {
                    const float val = acc[i][j][rg] + bz;
                    if (OUT_MODE == 0) {
                        ((float*)Cout)[(size_t)row * Nn + col] = val;
                    } else {
                        const int sec = col >> 8;
                        const int hh = (col >> 5) & 7;
                        const int d = col & 31;
                        ((unsigned short*)Cout)[(size_t)sec * M * 256 + (size_t)hh * M * 32
                                                + (size_t)row * 32 + d] = f2b(val);
                    }
                }
            }
        }
    }
}

// Pass 1 via MFMA: block -> head h = blockIdx&7 (XCD-pinned). 4 waves x 16 queries.
// sched_barrier(0) pins ALL 16 gathers before the MFMA chain (R9's plain preload
// was silently sunk by the scheduler: VGPR stayed 32, no delta).
__launch_bounds__(256, 4)
__global__ void attn_logits4(const unsigned short* __restrict__ qh,
                             const unsigned short* __restrict__ kh,
                             const int* __restrict__ index_1,
                             unsigned short* __restrict__ wh) {
    const int h = blockIdx.x & 7;
    const int slice = blockIdx.x >> 3;
    const int w = threadIdx.x >> 6;
    const int l = threadIdx.x & 63;
    const int col = l & 15;
    const int krow = l >> 4;
    const int qbase = slice * 64 + w * 16;

    const unsigned short* qhb = qh + (size_t)h * NQ * 32;
    const unsigned short* khb = kh + (size_t)h * NQ * 32;

    int qcol = qbase + col; qcol = qcol < NQ ? qcol : NQ - 1;
    const bf16x8_t bfrag = *reinterpret_cast<const bf16x8_t*>(qhb + (size_t)qcol * 32 + krow * 8);

    int idx[16];
#pragma unroll
    for (int j = 0; j < 16; ++j) {
        int qj = qbase + j; qj = qj < NQ ? qj : NQ - 1;
        idx[j] = index_1[(size_t)qj * 16 + col];
    }

    // phase 1: issue all 16 gathers; barrier prevents the scheduler sinking them
    bf16x8_t afr[16];
#pragma unroll
    for (int j = 0; j < 16; ++j)
        afr[j] = *reinterpret_cast<const bf16x8_t*>(khb + (size_t)idx[j] * 32 + krow * 8);
    __builtin_amdgcn_sched_barrier(0);

    // phase 2: MFMA chain, keep own column
    float s0 = 0.f, s1 = 0.f, s2 = 0.f, s3 = 0.f;
#pragma unroll
    for (int j = 0; j < 16; ++j) {
        const f32x4_t d = __builtin_amdgcn_mfma_f32_16x16x32_bf16(afr[j], bfrag, (f32x4_t)0.f, 0, 0, 0);
        const bool mine = (col == j);
        s0 = mine ? d[0] : s0;
        s1 = mine ? d[1] : s1;
        s2 = mine ? d[2] : s2;
        s3 = mine ? d[3] : s3;
    }

    float mx = fmaxf(fmaxf(s0, s1), fmaxf(s2, s3));
    mx = fmaxf(mx, __shfl_xor(mx, 16, 64));
    mx = fmaxf(mx, __shfl_xor(mx, 32, 64));
    float e0 = __expf(s0 - mx), e1 = __expf(s1 - mx), e2 = __expf(s2 - mx), e3 = __expf(s3 - mx);
    float sm = e0 + e1 + e2 + e3;
    sm += __shfl_xor(sm, 16, 64);
    sm += __shfl_xor(sm, 32, 64);
    const float inv = 1.f / sm;

    if (qbase + col < NQ) {
        const uint32_t d0 = (uint32_t)f2b(e0 * inv) | ((uint32_t)f2b(e1 * inv) << 16);
        const uint32_t d1 = (uint32_t)f2b(e2 * inv) | ((uint32_t)f2b(e3 * inv) << 16);
        *reinterpret_cast<uint2*>(wh + (size_t)h * NQ * 16 + (size_t)(qbase + col) * 16 + krow * 4)
            = make_uint2(d0, d1);
    }
}

// Pass 2 (head-split): x[i] (head h part) = sum_m w[h][i][m] * vh[h][nbr[m]].
// Same forced 16-deep preload of v-fragments.
__launch_bounds__(256, 4)
__global__ void attn_out3(const unsigned short* __restrict__ vh,
                          const unsigned short* __restrict__ wh,
                          const int* __restrict__ index_1,
                          unsigned short* __restrict__ xh) {
    const int h = blockIdx.x & 7;
    const int slice = blockIdx.x >> 3;
    const int w = threadIdx.x >> 6;
    const int l = threadIdx.x & 63;
    const int g = l >> 3;
    const int p = l & 7;
    int i = slice * 32 + w * 8 + g;
    const bool valid = i < NQ;
    if (!valid) i = 0;

    const int4* ip = reinterpret_cast<const int4*>(index_1 + (size_t)i * 16);
    const int4 n0 = ip[0], n1 = ip[1], n2 = ip[2], n3 = ip[3];
    const int nbr[16] = { n0.x, n0.y, n0.z, n0.w, n1.x, n1.y, n1.z, n1.w,
                          n2.x, n2.y, n2.z, n2.w, n3.x, n3.y, n3.z, n3.w };

    const unsigned short* vhb = vh + (size_t)h * NQ * 32;

    // phase 1: issue all 16 v-gathers + the weight load; pin before use
    ushort4 vreg[16];
#pragma unroll
    for (int m = 0; m < 16; ++m)
        vreg[m] = *reinterpret_cast<const ushort4*>(vhb + (size_t)nbr[m] * 32 + p * 4);
    const uint32_t* whp = (const uint32_t*)wh + (size_t)h * NQ * 8 + (size_t)i * 8;
    const uint4 w0 = *reinterpret_cast<const uint4*>(whp);
    const uint4 w1 = *reinterpret_cast<const uint4*>(whp + 4);
    __builtin_amdgcn_sched_barrier(0);

    const uint32_t wd[8] = { w0.x, w0.y, w0.z, w0.w, w1.x, w1.y, w1.z, w1.w };
    float wt[16];
#pragma unroll
    for (int j = 0; j < 8; ++j) up2(wd[j], wt[2 * j], wt[2 * j + 1]);

    float ax = 0.f, ay = 0.f, az = 0.f, aw = 0.f;
#pragma unroll
    for (int m = 0; m < 16; ++m) {
        ax += wt[m] * b2f(vreg[m].x); ay += wt[m] * b2f(vreg[m].y);
        az += wt[m] * b2f(vreg[m].z); aw += wt[m] * b2f(vreg[m].w);
    }
    if (valid) {
        ushort4 o;
        o.x = f2b(ax); o.y = f2b(ay); o.z = f2b(az); o.w = f2b(aw);
        *reinterpret_cast<ushort4*>(xh + (size_t)h * NQ * 32 + (size_t)i * 32 + p * 4) = o;
    }
}

extern "C" void kernel_launch(void* const* d_in, const int* in_sizes, int n_in,
                              void* d_out, int out_size, void* d_ws, size_t ws_size,
                              hipStream_t stream) {
    const float* feats   = (const float*)d_in[0];
    const int*   index_1 = (const int*)d_in[3];
    const float* qkv_w   = (const float*)d_in[6];
    const float* qkv_b   = (const float*)d_in[7];
    const float* proj_w  = (const float*)d_in[8];
    const float* proj_b  = (const float*)d_in[9];
    float* out = (float*)d_out;

    const int N = NQ, DIM = 256, QKVD = 768;

    unsigned short* featsb = (unsigned short*)d_ws;                // N*256
    unsigned short* qkvwb  = featsb + (size_t)N * DIM;             // 768*256
    unsigned short* projwb = qkvwb + (size_t)QKVD * DIM;           // 256*256
    float*          qkvbS  = (float*)(projwb + (size_t)DIM * DIM); // 768 floats
    unsigned short* qkvh   = (unsigned short*)(qkvbS + QKVD);      // 3*N*256 head-major q|k|v
    unsigned short* qh     = qkvh;
    unsigned short* kh     = qkvh + (size_t)N * DIM;
    unsigned short* vh     = qkvh + (size_t)2 * N * DIM;
    unsigned short* xh     = qkvh + (size_t)3 * N * DIM;           // N*256 head-major
    unsigned short* wh     = xh + (size_t)N * DIM;                 // N*128 head-major

    const int prepQuads = N * 256 / 4 + 49152 + 16384 + 192;
    prep_all<<<(prepQuads + 255) / 256, 256, 0, stream>>>(
        feats, qkv_w, proj_w, qkv_b, featsb, qkvwb, projwb, qkvbS);

    const int nRow = (N + 127) / 128;           // 391
    const int nRowPad = ((nRow + 7) / 8) * 8;   // 392
    const int logitsBlocks = ((N + 63) / 64) * 8;  // 782 * 8
    const int outBlocks    = ((N + 31) / 32) * 8;  // 1563 * 8

    // 1) qkv = feats @ qkv_w.T + qkv_bS -> head-major q|k|v bf16 (q pre-scaled)
    gemm_bf16<1, false><<<nRowPad * (QKVD / 128), 256, 0, stream>>>(featsb, qkvwb, qkvbS, qkvh, N, QKVD, DIM);
    // 2a) logits + softmax -> weights (head-split, XCD-pinned, MFMA, forced preload)
    attn_logits4<<<logitsBlocks, 256, 0, stream>>>(qh, kh, index_1, wh);
    // 2b) weighted V gather -> x (head-split, XCD-pinned, forced preload)
    attn_out3<<<outBlocks, 256, 0, stream>>>(vh, wh, index_1, xh);
    // 3) out = x @ proj_w.T + proj_b (fp32), A head-major
    gemm_bf16<0, true><<<nRowPad * (DIM / 128), 256, 0, stream>>>(xh, projwb, proj_b, out, N, DIM, DIM);
}